// Round 3
// baseline (228.857 us; speedup 1.0000x reference)
//
#include <hip/hip_runtime.h>
#include <hip/hip_bf16.h>

// CausalMultiHeadSelfAttention, MI355X gfx950.
// I/O fp32, internal bf16 MFMA.
// R14: attn is LDS-BW bound (R13 arithmetic: ~3.1 GB of bank traffic ≈ the
// whole 69.5 µs; MfmaUtil 22% / VALUBusy 26% both wait on the LDS pipe).
// Fix: 32 q-rows per wave (Q-tile 128, 4 waves) — the block-shared K/V
// fragment reads (16 KB/wave/iter) now feed 2x the MFMA work, cutting LDS
// bytes/FLOP 1.7x (3.1 -> 1.9 GB). 512 blocks, pairs {31-a, a} = 66 iters
// per CU slot, longest first. Causal mask covers last TWO kv tiles.
// P path: verified R11 PTP=72 layout, doubled per q-group.

typedef __hip_bfloat16 bf16;
using s16x4 = __attribute__((ext_vector_type(4))) short;
using s16x8 = __attribute__((ext_vector_type(8))) short;
using f32x4 = __attribute__((ext_vector_type(4))) float;

#define SEQ 4096
#define DMODEL 1024
#define NHEADS 16
#define DK 64
#define LOG2_THETA 13.287712379549449f  // log2(10000)
#define SCALE_LOG2E 0.1803368801111244f // 0.125 * log2(e)

__device__ __forceinline__ void async16(const bf16* g, bf16* l) {
  __builtin_amdgcn_global_load_lds(
      (const __attribute__((address_space(1))) unsigned int*)g,
      (__attribute__((address_space(3))) unsigned int*)l, 16, 0, 0);
}

// fp32 -> bf16, 8 elems/thread. z=0: x (4M elems), z=1..4: weights (1M each).
__global__ __launch_bounds__(256)
void conv_kernel(const float* __restrict__ s0, const float* __restrict__ s1,
                 const float* __restrict__ s2, const float* __restrict__ s3,
                 const float* __restrict__ s4,
                 bf16* __restrict__ d0, bf16* __restrict__ d1,
                 bf16* __restrict__ d2, bf16* __restrict__ d3,
                 bf16* __restrict__ d4) {
  const int z = blockIdx.z;
  const float* s = (z == 0) ? s0 : (z == 1) ? s1 : (z == 2) ? s2 : (z == 3) ? s3 : s4;
  bf16* d = (z == 0) ? d0 : (z == 1) ? d1 : (z == 2) ? d2 : (z == 3) ? d3 : d4;
  const int n = (z == 0) ? SEQ * DMODEL : DMODEL * DMODEL;
  const int i = (blockIdx.x * 256 + threadIdx.x) * 8;
  if (i >= n) return;
  const float4 a = *(const float4*)(s + i);
  const float4 b = *(const float4*)(s + i + 4);
  union { bf16 h[8]; s16x8 v; } u;
  u.h[0] = __float2bfloat16(a.x); u.h[1] = __float2bfloat16(a.y);
  u.h[2] = __float2bfloat16(a.z); u.h[3] = __float2bfloat16(a.w);
  u.h[4] = __float2bfloat16(b.x); u.h[5] = __float2bfloat16(b.y);
  u.h[6] = __float2bfloat16(b.z); u.h[7] = __float2bfloat16(b.w);
  *(s16x8*)(d + i) = u.v;
}

// C = A[4096][1024] @ W^T.  mode 0/1: Q/K +RoPE -> [h][s][d] (mode 0 output
// pre-scaled by 0.125*log2e for the attn exp2).  mode 2: V -> Vt[h][d][s].
// mode 3: fp32 [s][n] -> Df.
__global__ __launch_bounds__(256)
void gemm_kernel(const bf16* __restrict__ A,
                 const bf16* __restrict__ W0, const bf16* __restrict__ W1,
                 const bf16* __restrict__ W2,
                 bf16* __restrict__ D0, bf16* __restrict__ D1,
                 bf16* __restrict__ D2, float* __restrict__ Df,
                 int mode_base) {
  const int mode = mode_base + (int)blockIdx.z;
  const bf16* __restrict__ W = (mode == 1) ? W1 : (mode == 2) ? W2 : W0;
  bf16* __restrict__ D = (mode == 1) ? D1 : (mode == 2) ? D2 : D0;

  const int tid  = threadIdx.x;
  const int lane = tid & 63;
  const int wave = tid >> 6;
  const int wm = wave >> 1, wn = wave & 1;
  const int quad = lane >> 4, l16 = lane & 15;
  const int m0 = blockIdx.x * 128;
  const int n0 = blockIdx.y * 128;

  __shared__ __align__(16) bf16 As[128 * 32];
  __shared__ __align__(16) bf16 Bs[128 * 32];
  __shared__ __align__(16) bf16 Es[4][64 * 64];  // per-wave epilogue staging

  f32x4 acc[4][4] = {};

  const int ldrow = lane >> 2;
  const int ldcol = (lane & 3) * 8;

  for (int k0 = 0; k0 < DMODEL; k0 += 32) {
#pragma unroll
    for (int c = 0; c < 2; ++c) {
      const int chunk = wave * 2 + c;
      const int row = chunk * 16 + ldrow;
      async16(&A[(size_t)(m0 + row) * DMODEL + k0 + ldcol], &As[chunk * 512]);
      async16(&W[(size_t)(n0 + row) * DMODEL + k0 + ldcol], &Bs[chunk * 512]);
    }
    __syncthreads();

    s16x8 af[4], bfr[4];
#pragma unroll
    for (int i = 0; i < 4; ++i)
      af[i] = *(const s16x8*)&As[(wm * 64 + i * 16 + l16) * 32 + quad * 8];
#pragma unroll
    for (int j = 0; j < 4; ++j)
      bfr[j] = *(const s16x8*)&Bs[(wn * 64 + j * 16 + l16) * 32 + quad * 8];
#pragma unroll
    for (int i = 0; i < 4; ++i)
#pragma unroll
      for (int j = 0; j < 4; ++j)
        acc[i][j] = __builtin_amdgcn_mfma_f32_16x16x32_bf16(af[i], bfr[j],
                                                            acc[i][j], 0, 0, 0);
    __syncthreads();
  }

  // ---- epilogue ----
  if (mode == 3) {  // fp32 out: direct stores (64B quad segments)
#pragma unroll
    for (int i = 0; i < 4; ++i)
#pragma unroll
      for (int j = 0; j < 4; ++j) {
        const int col = n0 + wn * 64 + j * 16 + l16;
#pragma unroll
        for (int r = 0; r < 4; ++r) {
          const int srow = m0 + wm * 64 + i * 16 + quad * 4 + r;
          Df[(size_t)srow * DMODEL + col] = acc[i][j][r];
        }
      }
    return;
  }

  if (mode == 2) {  // transposed dump: Es[d_local][s_local]
#pragma unroll
    for (int i = 0; i < 4; ++i)
#pragma unroll
      for (int j = 0; j < 4; ++j)
#pragma unroll
        for (int r = 0; r < 4; ++r)
          Es[wave][(j * 16 + l16) * 64 + i * 16 + quad * 4 + r] =
              __float2bfloat16(acc[i][j][r]);
  } else {          // row-major dump: Es[s_local][d_local]
#pragma unroll
    for (int i = 0; i < 4; ++i)
#pragma unroll
      for (int j = 0; j < 4; ++j)
#pragma unroll
        for (int r = 0; r < 4; ++r)
          Es[wave][(i * 16 + quad * 4 + r) * 64 + j * 16 + l16] =
              __float2bfloat16(acc[i][j][r]);
  }
  __syncthreads();

  const int h = (n0 >> 6) + wn;         // wave's 64 cols = one head
  const int g  = lane >> 3;             // 0..7 row group
  const int c8 = (lane & 7) * 8;        // 0..56 col chunk (16B)

  if (mode == 2) {
#pragma unroll
    for (int t = 0; t < 8; ++t) {
      const int d = t * 8 + g;
      const s16x8 v = *(const s16x8*)&Es[wave][d * 64 + c8];
      *(s16x8*)&D[((size_t)h * DK + d) * SEQ + m0 + wm * 64 + c8] = v;
    }
  } else {
    // RoPE: pairs (c8+2k, c8+2k+1) in-lane; angle recurrence over t (rows +8).
    // mode 0 (Q): fold 0.125*log2e into cs/sn so attn can exp2 raw scores.
    const float qs = (mode == 0) ? SCALE_LOG2E : 1.0f;
    float sn[4], cs[4], s8[4], c8r[4], invf[4];
    const int srow0 = m0 + wm * 64 + g;
#pragma unroll
    for (int k = 0; k < 4; ++k) {
      const int p = (c8 >> 1) + k;
      invf[k] = __builtin_amdgcn_exp2f((float)p * (-2.0f / 64.0f) * LOG2_THETA);
      sincosf((float)srow0 * invf[k], &sn[k], &cs[k]);
      sincosf(8.0f * invf[k], &s8[k], &c8r[k]);
      sn[k] *= qs; cs[k] *= qs;
    }
#pragma unroll
    for (int t = 0; t < 8; ++t) {
      const int rl = t * 8 + g;
      union { bf16 h[8]; s16x8 v; } u, o;
      u.v = *(const s16x8*)&Es[wave][rl * 64 + c8];
#pragma unroll
      for (int k = 0; k < 4; ++k) {
        const float x0 = __bfloat162float(u.h[2 * k]);
        const float x1 = __bfloat162float(u.h[2 * k + 1]);
        o.h[2 * k]     = __float2bfloat16(x0 * cs[k] - x1 * sn[k]);
        o.h[2 * k + 1] = __float2bfloat16(x1 * cs[k] + x0 * sn[k]);
        const float ns_ = sn[k] * c8r[k] + cs[k] * s8[k];   // (scaled) recur
        cs[k] = cs[k] * c8r[k] - sn[k] * s8[k];
        sn[k] = ns_;
      }
      const int srow = m0 + wm * 64 + rl;
      *(s16x8*)&D[((size_t)h * SEQ + srow) * DK + c8] = o.v;
    }
  }
}

// Flash attention, shared-KV, double-buffered staging, SWAPPED QK operands
// (S^T in registers -> packed b64 P-transpose writes).
// R14: Q-tile 128 (4 waves x 32 q-rows, 2 groups of 16). K/V frag reads are
// read ONCE per wave-iter and feed both q-groups -> LDS bytes/FLOP 1.7x down.
// 512 blocks; balanced pairs {31-a, a} = 66 kv-iters per CU slot.
// No-max softmax: p = exp2(score) with Q pre-scaled; l via ones-B MFMA.
#define PTP 72  // padded Pt row stride (elems)
__global__ __launch_bounds__(256, 2)
void attn_kernel(const bf16* __restrict__ Q, const bf16* __restrict__ K,
                 const bf16* __restrict__ Vt, bf16* __restrict__ O) {
  const int tid  = threadIdx.x;
  const int lane = tid & 63;
  const int wave = tid >> 6;
  const int quad = lane >> 4, l16 = lane & 15;

  // balanced qb decode: blocks {i, i+256} co-reside; lengths sum to 66.
  const int i  = (int)blockIdx.x;        // 0..511
  const int j  = i & 255;
  const int h  = j & 15;
  const int a  = j >> 4;                 // 0..15
  const int qb = (i < 256) ? (31 - a) : a;   // longest first

  const bf16* __restrict__ Qh = Q + (size_t)h * SEQ * DK;
  const bf16* __restrict__ Kh = K + (size_t)h * SEQ * DK;
  const bf16* __restrict__ Vh = Vt + (size_t)h * DK * SEQ;

  __shared__ __align__(16) bf16 Ks[2][64 * 64];   // [buf][kv][d], swizzled
  __shared__ __align__(16) bf16 Vs[2][64 * 64];   // [buf][d][kv], swizzled
  __shared__ __align__(16) bf16 Pt[4][32 * PTP];  // per-wave P (A-layout)
  bf16* __restrict__ Ptw = Pt[wave];

  const short ONE = 0x3F80;
  const s16x8 ones = {ONE, ONE, ONE, ONE, ONE, ONE, ONE, ONE};

  // staging lane geometry: 8 rows x 8 chunks per async16 set
  const int srow = lane >> 3;            // 0..7
  const int schk = (lane & 7) ^ srow;    // XOR-swizzled global chunk
  const int xsw  = l16 & 7;              // reader-side swizzle key (K/V)

  const int q0 = qb * 128;
  const int qw = q0 + wave * 32;         // this wave's 32 Q rows
  const int nb = 2 * qb + 2;

  s16x8 aq[2][2];
#pragma unroll
  for (int g = 0; g < 2; ++g) {
    const size_t qr = (size_t)(qw + g * 16 + l16) * DK;
    aq[g][0] = *(const s16x8*)&Qh[qr + quad * 8];
    aq[g][1] = *(const s16x8*)&Qh[qr + 32 + quad * 8];
  }

  f32x4 oacc[2][4] = {};
  f32x4 lacc[2] = {};

  // prologue: stage tile 0 into buffer 0
  {
    const bf16* kg = Kh;                 // kv0 = 0
#pragma unroll
    for (int c = 0; c < 2; ++c) {
      const int chunk = wave * 2 + c;
      async16(kg + (size_t)(chunk * 8 + srow) * 64 + schk * 8,
              &Ks[0][chunk * 512]);
      async16(Vh + (size_t)(chunk * 8 + srow) * SEQ + schk * 8,
              &Vs[0][chunk * 512]);
    }
  }
  __syncthreads();

  for (int kb = 0; kb < nb; ++kb) {
    const int cur = kb & 1;
    // prefetch next tile into the other buffer (covered by this iter's work)
    if (kb + 1 < nb) {
      const int nxt = cur ^ 1;
      const int kv1 = (kb + 1) * 64;
      const bf16* kg = Kh + (size_t)kv1 * DK;
#pragma unroll
      for (int c = 0; c < 2; ++c) {
        const int chunk = wave * 2 + c;
        async16(kg + (size_t)(chunk * 8 + srow) * 64 + schk * 8,
                &Ks[nxt][chunk * 512]);
        async16(Vh + (size_t)(chunk * 8 + srow) * SEQ + kv1 + schk * 8,
                &Vs[nxt][chunk * 512]);
      }
    }

    // S^T = K * Q^T: K tile as A-operand, Q as B-operand (same fragments).
    // K frags read ONCE, used for both q-groups.
    // C-layout: row (quad*4+r) = kv_local within hh-block, col l16 = q_local.
    f32x4 sc[2][4] = {};
    __builtin_amdgcn_s_setprio(1);
#pragma unroll
    for (int hh = 0; hh < 4; ++hh) {
      const bf16* kr = &Ks[cur][(hh * 16 + l16) * 64];
      const s16x8 ak0 = *(const s16x8*)&kr[(quad ^ xsw) * 8];
      const s16x8 ak1 = *(const s16x8*)&kr[((quad + 4) ^ xsw) * 8];
#pragma unroll
      for (int g = 0; g < 2; ++g) {
        sc[g][hh] = __builtin_amdgcn_mfma_f32_16x16x32_bf16(ak0, aq[g][0], sc[g][hh], 0, 0, 0);
        sc[g][hh] = __builtin_amdgcn_mfma_f32_16x16x32_bf16(ak1, aq[g][1], sc[g][hh], 0, 0, 0);
      }
    }
    __builtin_amdgcn_s_setprio(0);

    // causal mask on the last TWO kv tiles (kv rel offset 0 or 64)
    if (kb >= nb - 2) {
      const int rel = (kb - (nb - 2)) * 64;  // 0 or 64
#pragma unroll
      for (int g = 0; g < 2; ++g) {
        const int lim = wave * 32 + g * 16 + l16 - rel - quad * 4;
#pragma unroll
        for (int hh = 0; hh < 4; ++hh)
#pragma unroll
          for (int r = 0; r < 4; ++r)
            if (hh * 16 + r > lim) sc[g][hh][r] = -1e30f;
      }
    }

    // p = exp2(score) (Q pre-scaled); raw v_exp_f32 — ocml's subnormal
    // fixup is dead weight here (masked -1e30 -> hard 0 from HW).
    // Each lane's r=0..3 are 4 consecutive kv columns of q-row l16
    // -> ONE packed b64 write per (g,hh).
    s16x8 ap[2][2];
#pragma unroll
    for (int g = 0; g < 2; ++g) {
#pragma unroll
      for (int hh = 0; hh < 4; ++hh) {
        union { bf16 b[4]; s16x4 v; } pk;
#pragma unroll
        for (int r = 0; r < 4; ++r)
          pk.b[r] = __float2bfloat16(__builtin_amdgcn_exp2f(sc[g][hh][r]));
        *(s16x4*)&Ptw[(g * 16 + l16) * PTP + hh * 16 + quad * 4] = pk.v;
      }
      ap[g][0] = *(const s16x8*)&Ptw[(g * 16 + l16) * PTP + quad * 8];
      ap[g][1] = *(const s16x8*)&Ptw[(g * 16 + l16) * PTP + 32 + quad * 8];
    }

    // PV from swizzled Vt tile + row-sum(l) via ones-B.
    // V frags read ONCE, used for both q-groups.
    __builtin_amdgcn_s_setprio(1);
#pragma unroll
    for (int ns = 0; ns < 4; ++ns) {
      const bf16* vr = &Vs[cur][(ns * 16 + l16) * 64];
      const s16x8 bv0 = *(const s16x8*)&vr[(quad ^ xsw) * 8];
      const s16x8 bv1 = *(const s16x8*)&vr[((quad + 4) ^ xsw) * 8];
#pragma unroll
      for (int g = 0; g < 2; ++g) {
        oacc[g][ns] = __builtin_amdgcn_mfma_f32_16x16x32_bf16(ap[g][0], bv0, oacc[g][ns], 0, 0, 0);
        oacc[g][ns] = __builtin_amdgcn_mfma_f32_16x16x32_bf16(ap[g][1], bv1, oacc[g][ns], 0, 0, 0);
      }
    }
#pragma unroll
    for (int g = 0; g < 2; ++g) {
      lacc[g] = __builtin_amdgcn_mfma_f32_16x16x32_bf16(ap[g][0], ones, lacc[g], 0, 0, 0);
      lacc[g] = __builtin_amdgcn_mfma_f32_16x16x32_bf16(ap[g][1], ones, lacc[g], 0, 0, 0);
    }
    __builtin_amdgcn_s_setprio(0);

    // ONE barrier: drains the prefetch (covered by compute above) and
    // protects buf[cur] from restaging next iteration.
    __syncthreads();
  }

  // epilogue: wave-private; stage 32x64 to Ptw, store coalesced.
  // 1/l via v_rcp (1 ulp, swallowed by bf16) instead of full divides.
#pragma unroll
  for (int g = 0; g < 2; ++g) {
    float rl[4];
#pragma unroll
    for (int r = 0; r < 4; ++r) rl[r] = __builtin_amdgcn_rcpf(lacc[g][r]);
#pragma unroll
    for (int ns = 0; ns < 4; ++ns)
#pragma unroll
      for (int r = 0; r < 4; ++r)
        Ptw[(g * 16 + quad * 4 + r) * PTP + ns * 16 + l16] =
            __float2bfloat16(oacc[g][ns][r] * rl[r]);
  }
  const int g8 = lane >> 3, c8 = (lane & 7) * 8;
#pragma unroll
  for (int t = 0; t < 4; ++t) {
    const int row = t * 8 + g8;
    const s16x8 v = *(const s16x8*)&Ptw[row * PTP + c8];
    *(s16x8*)&O[(size_t)(qw + row) * DMODEL + h * DK + c8] = v;
  }
}

extern "C" void kernel_launch(void* const* d_in, const int* in_sizes, int n_in,
                              void* d_out, int out_size, void* d_ws, size_t ws_size,
                              hipStream_t stream) {
  const float* x  = (const float*)d_in[0];
  const float* Wq = (const float*)d_in[1];
  const float* Wk = (const float*)d_in[2];
  const float* Wv = (const float*)d_in[3];
  const float* Wo = (const float*)d_in[4];
  float* out = (float*)d_out;

  bf16* ws = (bf16*)d_ws;
  bf16* xb   = ws;
  bf16* Wqb  = xb  + (size_t)SEQ * DMODEL;
  bf16* Wkb  = Wqb + (size_t)DMODEL * DMODEL;
  bf16* Wvb  = Wkb + (size_t)DMODEL * DMODEL;
  bf16* Wob  = Wvb + (size_t)DMODEL * DMODEL;
  bf16* Qb   = Wob + (size_t)DMODEL * DMODEL;
  bf16* Kb   = Qb  + (size_t)SEQ * DMODEL;
  bf16* Vtb  = Kb  + (size_t)SEQ * DMODEL;
  bf16* Attn = Vtb + (size_t)SEQ * DMODEL;

  conv_kernel<<<dim3(SEQ * DMODEL / (256 * 8), 1, 5), 256, 0, stream>>>(
      x, Wq, Wk, Wv, Wo, xb, Wqb, Wkb, Wvb, Wob);
  gemm_kernel<<<dim3(SEQ / 128, DMODEL / 128, 3), 256, 0, stream>>>(
      xb, Wqb, Wkb, Wvb, Qb, Kb, Vtb, out, 0);
  attn_kernel<<<dim3(32 * NHEADS), 256, 0, stream>>>(Qb, Kb, Vtb, Attn);
  gemm_kernel<<<dim3(SEQ / 128, DMODEL / 128, 1), 256, 0, stream>>>(
      Attn, Wob, Wob, Wob, Attn, Attn, Attn, out, 3);
}

// Round 4
// 208.108 us; speedup vs baseline: 1.0997x; 1.0997x over previous
//
#include <hip/hip_runtime.h>
#include <hip/hip_bf16.h>

// CausalMultiHeadSelfAttention, MI355X gfx950.
// I/O fp32, internal bf16 MFMA.
// R15: revert to R13 geometry (1024 blocks, 64-q tiles, balanced decode),
// restructure inner loop as 2x2 wave split: wave (wq,wk) owns 32q x 32kv.
// With 16-kv QK output blocks, swapped-QK score layout IS the A-fragment
// of v_mfma_f32_16x16x16_bf16 -> P LDS round-trip eliminated; l via VALU
// adds + end-of-block shuffle reduce (ones-MFMA dropped); K/V frag reads
// halved. Cross-wave O/l reduction once per block through LDS (32KB total).
// R14 post-mortem: LDS-BW theory wrong — concurrency dominates; keep 1024
// blocks. R13 counters: MfmaUtil 22 / VALUBusy 26 / Occ 24 — chain-bound.

typedef __hip_bfloat16 bf16;
using s16x4 = __attribute__((ext_vector_type(4))) short;
using s16x8 = __attribute__((ext_vector_type(8))) short;
using f32x4 = __attribute__((ext_vector_type(4))) float;

#define SEQ 4096
#define DMODEL 1024
#define NHEADS 16
#define DK 64
#define LOG2_THETA 13.287712379549449f  // log2(10000)
#define SCALE_LOG2E 0.1803368801111244f // 0.125 * log2(e)

#if defined(__has_builtin)
#if __has_builtin(__builtin_amdgcn_mfma_f32_16x16x16bf16_1k)
#define HAVE_MFMA16 1
#endif
#endif

__device__ __forceinline__ f32x4 mfma16(s16x4 a, s16x4 b, f32x4 c) {
#ifdef HAVE_MFMA16
  return __builtin_amdgcn_mfma_f32_16x16x16bf16_1k(a, b, c, 0, 0, 0);
#else
  asm volatile("v_mfma_f32_16x16x16_bf16 %0, %1, %2, %0"
               : "+v"(c) : "v"(a), "v"(b));
  return c;
#endif
}

__device__ __forceinline__ void async16(const bf16* g, bf16* l) {
  __builtin_amdgcn_global_load_lds(
      (const __attribute__((address_space(1))) unsigned int*)g,
      (__attribute__((address_space(3))) unsigned int*)l, 16, 0, 0);
}

// fp32 -> bf16, 8 elems/thread. z=0: x (4M elems), z=1..4: weights (1M each).
__global__ __launch_bounds__(256)
void conv_kernel(const float* __restrict__ s0, const float* __restrict__ s1,
                 const float* __restrict__ s2, const float* __restrict__ s3,
                 const float* __restrict__ s4,
                 bf16* __restrict__ d0, bf16* __restrict__ d1,
                 bf16* __restrict__ d2, bf16* __restrict__ d3,
                 bf16* __restrict__ d4) {
  const int z = blockIdx.z;
  const float* s = (z == 0) ? s0 : (z == 1) ? s1 : (z == 2) ? s2 : (z == 3) ? s3 : s4;
  bf16* d = (z == 0) ? d0 : (z == 1) ? d1 : (z == 2) ? d2 : (z == 3) ? d3 : d4;
  const int n = (z == 0) ? SEQ * DMODEL : DMODEL * DMODEL;
  const int i = (blockIdx.x * 256 + threadIdx.x) * 8;
  if (i >= n) return;
  const float4 a = *(const float4*)(s + i);
  const float4 b = *(const float4*)(s + i + 4);
  union { bf16 h[8]; s16x8 v; } u;
  u.h[0] = __float2bfloat16(a.x); u.h[1] = __float2bfloat16(a.y);
  u.h[2] = __float2bfloat16(a.z); u.h[3] = __float2bfloat16(a.w);
  u.h[4] = __float2bfloat16(b.x); u.h[5] = __float2bfloat16(b.y);
  u.h[6] = __float2bfloat16(b.z); u.h[7] = __float2bfloat16(b.w);
  *(s16x8*)(d + i) = u.v;
}

// C = A[4096][1024] @ W^T.  mode 0/1: Q/K +RoPE -> [h][s][d] (mode 0 output
// pre-scaled by 0.125*log2e for the attn exp2).  mode 2: V -> Vt[h][d][s].
// mode 3: fp32 [s][n] -> Df.
__global__ __launch_bounds__(256)
void gemm_kernel(const bf16* __restrict__ A,
                 const bf16* __restrict__ W0, const bf16* __restrict__ W1,
                 const bf16* __restrict__ W2,
                 bf16* __restrict__ D0, bf16* __restrict__ D1,
                 bf16* __restrict__ D2, float* __restrict__ Df,
                 int mode_base) {
  const int mode = mode_base + (int)blockIdx.z;
  const bf16* __restrict__ W = (mode == 1) ? W1 : (mode == 2) ? W2 : W0;
  bf16* __restrict__ D = (mode == 1) ? D1 : (mode == 2) ? D2 : D0;

  const int tid  = threadIdx.x;
  const int lane = tid & 63;
  const int wave = tid >> 6;
  const int wm = wave >> 1, wn = wave & 1;
  const int quad = lane >> 4, l16 = lane & 15;
  const int m0 = blockIdx.x * 128;
  const int n0 = blockIdx.y * 128;

  __shared__ __align__(16) bf16 As[128 * 32];
  __shared__ __align__(16) bf16 Bs[128 * 32];
  __shared__ __align__(16) bf16 Es[4][64 * 64];  // per-wave epilogue staging

  f32x4 acc[4][4] = {};

  const int ldrow = lane >> 2;
  const int ldcol = (lane & 3) * 8;

  for (int k0 = 0; k0 < DMODEL; k0 += 32) {
#pragma unroll
    for (int c = 0; c < 2; ++c) {
      const int chunk = wave * 2 + c;
      const int row = chunk * 16 + ldrow;
      async16(&A[(size_t)(m0 + row) * DMODEL + k0 + ldcol], &As[chunk * 512]);
      async16(&W[(size_t)(n0 + row) * DMODEL + k0 + ldcol], &Bs[chunk * 512]);
    }
    __syncthreads();

    s16x8 af[4], bfr[4];
#pragma unroll
    for (int i = 0; i < 4; ++i)
      af[i] = *(const s16x8*)&As[(wm * 64 + i * 16 + l16) * 32 + quad * 8];
#pragma unroll
    for (int j = 0; j < 4; ++j)
      bfr[j] = *(const s16x8*)&Bs[(wn * 64 + j * 16 + l16) * 32 + quad * 8];
#pragma unroll
    for (int i = 0; i < 4; ++i)
#pragma unroll
      for (int j = 0; j < 4; ++j)
        acc[i][j] = __builtin_amdgcn_mfma_f32_16x16x32_bf16(af[i], bfr[j],
                                                            acc[i][j], 0, 0, 0);
    __syncthreads();
  }

  // ---- epilogue ----
  if (mode == 3) {  // fp32 out: direct stores (64B quad segments)
#pragma unroll
    for (int i = 0; i < 4; ++i)
#pragma unroll
      for (int j = 0; j < 4; ++j) {
        const int col = n0 + wn * 64 + j * 16 + l16;
#pragma unroll
        for (int r = 0; r < 4; ++r) {
          const int srow = m0 + wm * 64 + i * 16 + quad * 4 + r;
          Df[(size_t)srow * DMODEL + col] = acc[i][j][r];
        }
      }
    return;
  }

  if (mode == 2) {  // transposed dump: Es[d_local][s_local]
#pragma unroll
    for (int i = 0; i < 4; ++i)
#pragma unroll
      for (int j = 0; j < 4; ++j)
#pragma unroll
        for (int r = 0; r < 4; ++r)
          Es[wave][(j * 16 + l16) * 64 + i * 16 + quad * 4 + r] =
              __float2bfloat16(acc[i][j][r]);
  } else {          // row-major dump: Es[s_local][d_local]
#pragma unroll
    for (int i = 0; i < 4; ++i)
#pragma unroll
      for (int j = 0; j < 4; ++j)
#pragma unroll
        for (int r = 0; r < 4; ++r)
          Es[wave][(i * 16 + quad * 4 + r) * 64 + j * 16 + l16] =
              __float2bfloat16(acc[i][j][r]);
  }
  __syncthreads();

  const int h = (n0 >> 6) + wn;         // wave's 64 cols = one head
  const int g  = lane >> 3;             // 0..7 row group
  const int c8 = (lane & 7) * 8;        // 0..56 col chunk (16B)

  if (mode == 2) {
#pragma unroll
    for (int t = 0; t < 8; ++t) {
      const int d = t * 8 + g;
      const s16x8 v = *(const s16x8*)&Es[wave][d * 64 + c8];
      *(s16x8*)&D[((size_t)h * DK + d) * SEQ + m0 + wm * 64 + c8] = v;
    }
  } else {
    // RoPE: pairs (c8+2k, c8+2k+1) in-lane; angle recurrence over t (rows +8).
    // mode 0 (Q): fold 0.125*log2e into cs/sn so attn can exp2 raw scores.
    const float qs = (mode == 0) ? SCALE_LOG2E : 1.0f;
    float sn[4], cs[4], s8[4], c8r[4], invf[4];
    const int srow0 = m0 + wm * 64 + g;
#pragma unroll
    for (int k = 0; k < 4; ++k) {
      const int p = (c8 >> 1) + k;
      invf[k] = __builtin_amdgcn_exp2f((float)p * (-2.0f / 64.0f) * LOG2_THETA);
      sincosf((float)srow0 * invf[k], &sn[k], &cs[k]);
      sincosf(8.0f * invf[k], &s8[k], &c8r[k]);
      sn[k] *= qs; cs[k] *= qs;
    }
#pragma unroll
    for (int t = 0; t < 8; ++t) {
      const int rl = t * 8 + g;
      union { bf16 h[8]; s16x8 v; } u, o;
      u.v = *(const s16x8*)&Es[wave][rl * 64 + c8];
#pragma unroll
      for (int k = 0; k < 4; ++k) {
        const float x0 = __bfloat162float(u.h[2 * k]);
        const float x1 = __bfloat162float(u.h[2 * k + 1]);
        o.h[2 * k]     = __float2bfloat16(x0 * cs[k] - x1 * sn[k]);
        o.h[2 * k + 1] = __float2bfloat16(x1 * cs[k] + x0 * sn[k]);
        const float ns_ = sn[k] * c8r[k] + cs[k] * s8[k];   // (scaled) recur
        cs[k] = cs[k] * c8r[k] - sn[k] * s8[k];
        sn[k] = ns_;
      }
      const int srow = m0 + wm * 64 + rl;
      *(s16x8*)&D[((size_t)h * SEQ + srow) * DK + c8] = o.v;
    }
  }
}

// Flash attention. Block = one 64-q tile (1024 blocks, R13 balanced decode).
// 2x2 wave split: wave (wq,wk) computes 32q x 32kv of each 64x64 tile.
// Swapped QK (A=K slice) gives sc[gq][hh][r] = P[q=gq*16+l16][kv=hh*16+quad*4+r]
// which is EXACTLY the 16x16x16 MFMA A-fragment -> no P LDS round-trip.
// l accumulated per-lane (VALU), quad-shfl-reduced + cross-wave summed at end.
// Cross-wave O reduction via LDS once per block. LDS = 32KB exactly.
__global__ __launch_bounds__(256, 4)
void attn_kernel(const bf16* __restrict__ Q, const bf16* __restrict__ K,
                 const bf16* __restrict__ Vt, bf16* __restrict__ O) {
  const int tid  = threadIdx.x;
  const int lane = tid & 63;
  const int wave = tid >> 6;
  const int quad = lane >> 4, l16 = lane & 15;
  const int wq = wave & 1;               // q-half owner
  const int wk = wave >> 1;              // kv-half owner

  // balanced qb decode: blocks {i, i+256, i+512, i+768} co-reside on one CU
  // under round-robin; their lengths sum to 130 for every i.
  const int i  = (int)blockIdx.x;        // 0..1023
  const int j  = i & 255;
  const int vv = 3 - (i >> 8);           // 3,2,1,0 -> longest first
  const int h  = j & 15;
  const int a  = j >> 4;                 // 0..15
  const int qb = vv * 16 + ((vv & 1) ? (15 - a) : a);

  const bf16* __restrict__ Qh = Q + (size_t)h * SEQ * DK;
  const bf16* __restrict__ Kh = K + (size_t)h * SEQ * DK;
  const bf16* __restrict__ Vh = Vt + (size_t)h * DK * SEQ;

  // 32KB shared: loop phase = Ks[2][64*64] + Vs[2][64*64] (bf16, swizzled).
  // epilogue phase (after final barrier) re-uses it as:
  //   Ored f32[64][66] @0 (16896B) | lred f32[64] @16896 | Obuf bf16[64][72] @17408
  __shared__ __align__(16) char smemb[32768];
  bf16* __restrict__ smem = (bf16*)smemb;
  bf16* __restrict__ KsB = smem;          // [buf*4096]
  bf16* __restrict__ VsB = smem + 8192;   // [buf*4096]

  // staging lane geometry: 8 rows x 8 chunks per async16 set
  const int srow = lane >> 3;            // 0..7
  const int schk = (lane & 7) ^ srow;    // XOR-swizzled global chunk
  const int xsw  = l16 & 7;              // reader-side swizzle key

  const int q0 = qb * 64;
  const int qw = q0 + wq * 32;           // this wave's 32 Q rows
  const int nb = qb + 1;

  // Q fragments (B-operand): aq[gq][half]
  s16x8 aq[2][2];
#pragma unroll
  for (int gq = 0; gq < 2; ++gq) {
    const size_t qr = (size_t)(qw + gq * 16 + l16) * DK;
    aq[gq][0] = *(const s16x8*)&Qh[qr + quad * 8];
    aq[gq][1] = *(const s16x8*)&Qh[qr + 32 + quad * 8];
  }

  f32x4 oacc[2][4] = {};   // [gq][d-block]: O[q=gq*16+quad*4+r][d=ns*16+l16]
  float lsum[2] = {0.f, 0.f};  // per-lane partial l[q=gq*16+l16]

  // prologue: stage tile 0 into buffer 0
  {
#pragma unroll
    for (int c = 0; c < 2; ++c) {
      const int chunk = wave * 2 + c;
      async16(Kh + (size_t)(chunk * 8 + srow) * 64 + schk * 8,
              &KsB[chunk * 512]);
      async16(Vh + (size_t)(chunk * 8 + srow) * SEQ + schk * 8,
              &VsB[chunk * 512]);
    }
  }
  __syncthreads();

  for (int kb = 0; kb < nb; ++kb) {
    const int cur = kb & 1;
    // prefetch next tile into the other buffer (covered by this iter's work)
    if (kb + 1 < nb) {
      const int nxt = cur ^ 1;
      const int kv1 = (kb + 1) * 64;
      const bf16* kg = Kh + (size_t)kv1 * DK;
#pragma unroll
      for (int c = 0; c < 2; ++c) {
        const int chunk = wave * 2 + c;
        async16(kg + (size_t)(chunk * 8 + srow) * 64 + schk * 8,
                &KsB[nxt * 4096 + chunk * 512]);
        async16(Vh + (size_t)(chunk * 8 + srow) * SEQ + kv1 + schk * 8,
                &VsB[nxt * 4096 + chunk * 512]);
      }
    }

    const bf16* __restrict__ Ksc = &KsB[cur * 4096];
    const bf16* __restrict__ Vsc = &VsB[cur * 4096];

    // S^T = K*Q^T over this wave's 32-kv slice: per (gq,hh):
    // sc[gq][hh] D-layout: row quad*4+r = kv-local (within hh block), col l16 = q.
    f32x4 sc[2][2] = {};
    __builtin_amdgcn_s_setprio(1);
#pragma unroll
    for (int hh = 0; hh < 2; ++hh) {
      const bf16* kr = &Ksc[(wk * 32 + hh * 16 + l16) * 64];
      const s16x8 ak0 = *(const s16x8*)&kr[(quad ^ xsw) * 8];
      const s16x8 ak1 = *(const s16x8*)&kr[((quad + 4) ^ xsw) * 8];
#pragma unroll
      for (int gq = 0; gq < 2; ++gq) {
        sc[gq][hh] = __builtin_amdgcn_mfma_f32_16x16x32_bf16(ak0, aq[gq][0], sc[gq][hh], 0, 0, 0);
        sc[gq][hh] = __builtin_amdgcn_mfma_f32_16x16x32_bf16(ak1, aq[gq][1], sc[gq][hh], 0, 0, 0);
      }
    }
    __builtin_amdgcn_s_setprio(0);

    // causal mask on diagonal tile: kv > q
    if (kb == nb - 1) {
#pragma unroll
      for (int gq = 0; gq < 2; ++gq) {
        const int lim = wq * 32 + gq * 16 + l16 - wk * 32 - quad * 4;
#pragma unroll
        for (int hh = 0; hh < 2; ++hh)
#pragma unroll
          for (int r = 0; r < 4; ++r)
            if (hh * 16 + r > lim) sc[gq][hh][r] = -1e30f;
      }
    }

    // p = exp2(score) (Q pre-scaled, raw v_exp_f32). Packed s16x4 per (gq,hh)
    // IS the 16x16x16 A-fragment (A[row=l16][k=quad*4+i]) — no LDS, no shuffle.
    s16x4 ap[2][2];
#pragma unroll
    for (int gq = 0; gq < 2; ++gq) {
#pragma unroll
      for (int hh = 0; hh < 2; ++hh) {
        union { bf16 b[4]; s16x4 v; } pk;
        float ps = 0.f;
#pragma unroll
        for (int r = 0; r < 4; ++r) {
          const float p = __builtin_amdgcn_exp2f(sc[gq][hh][r]);
          pk.b[r] = __float2bfloat16(p);
          ps += p;
        }
        lsum[gq] += ps;
        ap[gq][hh] = pk.v;
      }
    }

    // PV via 16x16x16: B[k=kv=quad*4+i][col=d=l16] from Vt[d][kv] slice.
    __builtin_amdgcn_s_setprio(1);
#pragma unroll
    for (int hh = 0; hh < 2; ++hh) {
      const int cg = wk * 4 + hh * 2 + (quad >> 1);      // global 16B chunk
      const int eo = ((cg ^ xsw) << 3) + (quad & 1) * 4; // elem offset in row
#pragma unroll
      for (int ns = 0; ns < 4; ++ns) {
        const s16x4 bv = *(const s16x4*)&Vsc[(ns * 16 + l16) * 64 + eo];
#pragma unroll
        for (int gq = 0; gq < 2; ++gq)
          oacc[gq][ns] = mfma16(ap[gq][hh], bv, oacc[gq][ns]);
      }
    }
    __builtin_amdgcn_s_setprio(0);

    // ONE barrier: drains the prefetch (covered by compute above) and
    // protects buf[cur] from restaging next iteration.
    __syncthreads();
  }

  // ---- cross-wave (wk) reduction + store ----
  float* __restrict__ Ored = (float*)smemb;            // [64][66]
  float* __restrict__ lred = (float*)(smemb + 16896);  // [64]
  bf16*  __restrict__ Obuf = (bf16*)(smemb + 17408);   // [64][72]

  // quad-reduce l: after this every lane holds wave-partial l[q=gq*16+l16]
#pragma unroll
  for (int gq = 0; gq < 2; ++gq) {
    lsum[gq] += __shfl_xor(lsum[gq], 16);
    lsum[gq] += __shfl_xor(lsum[gq], 32);
  }

  if (wk == 0) {
    if (quad == 0)
#pragma unroll
      for (int gq = 0; gq < 2; ++gq)
        lred[wq * 32 + gq * 16 + l16] = lsum[gq];
  } else {
#pragma unroll
    for (int gq = 0; gq < 2; ++gq)
#pragma unroll
      for (int ns = 0; ns < 4; ++ns)
#pragma unroll
        for (int r = 0; r < 4; ++r)
          Ored[(wq * 32 + gq * 16 + quad * 4 + r) * 66 + ns * 16 + l16] =
              oacc[gq][ns][r];
  }
  __syncthreads();
  if (wk == 1 && quad == 0) {
#pragma unroll
    for (int gq = 0; gq < 2; ++gq)
      lred[wq * 32 + gq * 16 + l16] += lsum[gq];
  }
  __syncthreads();
  if (wk == 0) {
#pragma unroll
    for (int gq = 0; gq < 2; ++gq) {
      float rl[4];
#pragma unroll
      for (int r = 0; r < 4; ++r)
        rl[r] = __builtin_amdgcn_rcpf(lred[wq * 32 + gq * 16 + quad * 4 + r]);
#pragma unroll
      for (int ns = 0; ns < 4; ++ns)
#pragma unroll
        for (int r = 0; r < 4; ++r) {
          const int row = wq * 32 + gq * 16 + quad * 4 + r;
          const float v = oacc[gq][ns][r] + Ored[row * 66 + ns * 16 + l16];
          Obuf[row * 72 + ns * 16 + l16] = __float2bfloat16(v * rl[r]);
        }
    }
  }
  __syncthreads();
  // cooperative coalesced store: 64 rows x 128B, 2 passes of 256x16B
#pragma unroll
  for (int p = 0; p < 2; ++p) {
    const int row = p * 32 + (tid >> 3);
    const int c8 = (tid & 7) * 8;
    const s16x8 v = *(const s16x8*)&Obuf[row * 72 + c8];
    *(s16x8*)&O[(size_t)(q0 + row) * DMODEL + h * DK + c8] = v;
  }
}

extern "C" void kernel_launch(void* const* d_in, const int* in_sizes, int n_in,
                              void* d_out, int out_size, void* d_ws, size_t ws_size,
                              hipStream_t stream) {
  const float* x  = (const float*)d_in[0];
  const float* Wq = (const float*)d_in[1];
  const float* Wk = (const float*)d_in[2];
  const float* Wv = (const float*)d_in[3];
  const float* Wo = (const float*)d_in[4];
  float* out = (float*)d_out;

  bf16* ws = (bf16*)d_ws;
  bf16* xb   = ws;
  bf16* Wqb  = xb  + (size_t)SEQ * DMODEL;
  bf16* Wkb  = Wqb + (size_t)DMODEL * DMODEL;
  bf16* Wvb  = Wkb + (size_t)DMODEL * DMODEL;
  bf16* Wob  = Wvb + (size_t)DMODEL * DMODEL;
  bf16* Qb   = Wob + (size_t)DMODEL * DMODEL;
  bf16* Kb   = Qb  + (size_t)SEQ * DMODEL;
  bf16* Vtb  = Kb  + (size_t)SEQ * DMODEL;
  bf16* Attn = Vtb + (size_t)SEQ * DMODEL;

  conv_kernel<<<dim3(SEQ * DMODEL / (256 * 8), 1, 5), 256, 0, stream>>>(
      x, Wq, Wk, Wv, Wo, xb, Wqb, Wkb, Wvb, Wob);
  gemm_kernel<<<dim3(SEQ / 128, DMODEL / 128, 3), 256, 0, stream>>>(
      xb, Wqb, Wkb, Wvb, Qb, Kb, Vtb, out, 0);
  attn_kernel<<<dim3(64 * NHEADS), 256, 0, stream>>>(Qb, Kb, Vtb, Attn);
  gemm_kernel<<<dim3(SEQ / 128, DMODEL / 128, 1), 256, 0, stream>>>(
      Attn, Wob, Wob, Wob, Attn, Attn, Attn, out, 3);
}

// Round 5
// 187.087 us; speedup vs baseline: 1.2233x; 1.1124x over previous
//
#include <hip/hip_runtime.h>
#include <hip/hip_bf16.h>

// CausalMultiHeadSelfAttention, MI355X gfx950.
// I/O fp32, internal bf16 MFMA.
// R16: non-attn side is ~140us (~260 TF effective GEMM) — attack staging
// latency: gemm K-loop -> single-barrier double-buffer (stage(next) ->
// compute(cur) -> ONE barrier), buf1 aliased onto Es (LDS stays 48KB).
// mode-3 gemm -> dedicated gemmo_kernel, 64x128 tiles, 512 blocks (2/CU).
// attn: l-accum via mfma16(P, ones) instead of 16 VALU adds/iter (VALU was
// top pipe at 45%); epilogue shuffle-reduce dropped (l lands in oacc row
// layout). conv: grid-stride, exact block count.

typedef __hip_bfloat16 bf16;
using s16x4 = __attribute__((ext_vector_type(4))) short;
using s16x8 = __attribute__((ext_vector_type(8))) short;
using f32x4 = __attribute__((ext_vector_type(4))) float;

#define SEQ 4096
#define DMODEL 1024
#define NHEADS 16
#define DK 64
#define LOG2_THETA 13.287712379549449f  // log2(10000)
#define SCALE_LOG2E 0.1803368801111244f // 0.125 * log2(e)

#if defined(__has_builtin)
#if __has_builtin(__builtin_amdgcn_mfma_f32_16x16x16bf16_1k)
#define HAVE_MFMA16 1
#endif
#endif

__device__ __forceinline__ f32x4 mfma16(s16x4 a, s16x4 b, f32x4 c) {
#ifdef HAVE_MFMA16
  return __builtin_amdgcn_mfma_f32_16x16x16bf16_1k(a, b, c, 0, 0, 0);
#else
  asm volatile("v_mfma_f32_16x16x16_bf16 %0, %1, %2, %0"
               : "+v"(c) : "v"(a), "v"(b));
  return c;
#endif
}

__device__ __forceinline__ void async16(const bf16* g, bf16* l) {
  __builtin_amdgcn_global_load_lds(
      (const __attribute__((address_space(1))) unsigned int*)g,
      (__attribute__((address_space(3))) unsigned int*)l, 16, 0, 0);
}

// fp32 -> bf16, 8 elems/thread, grid-stride. z=0: x (4M), z=1..4: W (1M each).
__global__ __launch_bounds__(256)
void conv_kernel(const float* __restrict__ s0, const float* __restrict__ s1,
                 const float* __restrict__ s2, const float* __restrict__ s3,
                 const float* __restrict__ s4,
                 bf16* __restrict__ d0, bf16* __restrict__ d1,
                 bf16* __restrict__ d2, bf16* __restrict__ d3,
                 bf16* __restrict__ d4) {
  const int z = blockIdx.z;
  const float* s = (z == 0) ? s0 : (z == 1) ? s1 : (z == 2) ? s2 : (z == 3) ? s3 : s4;
  bf16* d = (z == 0) ? d0 : (z == 1) ? d1 : (z == 2) ? d2 : (z == 3) ? d3 : d4;
  const int n = (z == 0) ? SEQ * DMODEL : DMODEL * DMODEL;
  for (int i = (blockIdx.x * 256 + threadIdx.x) * 8; i < n; i += 512 * 256 * 8) {
    const float4 a = *(const float4*)(s + i);
    const float4 b = *(const float4*)(s + i + 4);
    union { bf16 h[8]; s16x8 v; } u;
    u.h[0] = __float2bfloat16(a.x); u.h[1] = __float2bfloat16(a.y);
    u.h[2] = __float2bfloat16(a.z); u.h[3] = __float2bfloat16(a.w);
    u.h[4] = __float2bfloat16(b.x); u.h[5] = __float2bfloat16(b.y);
    u.h[6] = __float2bfloat16(b.z); u.h[7] = __float2bfloat16(b.w);
    *(s16x8*)(d + i) = u.v;
  }
}

// C = A[4096][1024] @ W^T.  mode 0/1: Q/K +RoPE -> [h][s][d] (mode 0 output
// pre-scaled by 0.125*log2e for the attn exp2).  mode 2: V -> Vt[h][d][s].
// Single-barrier double-buffered K-loop; buf1 aliased under the Es epilogue
// staging so total LDS stays 48KB (3 blocks/CU).
__global__ __launch_bounds__(256)
void gemm_kernel(const bf16* __restrict__ A,
                 const bf16* __restrict__ W0, const bf16* __restrict__ W1,
                 const bf16* __restrict__ W2,
                 bf16* __restrict__ D0, bf16* __restrict__ D1,
                 bf16* __restrict__ D2) {
  const int mode = (int)blockIdx.z;
  const bf16* __restrict__ W = (mode == 1) ? W1 : (mode == 2) ? W2 : W0;
  bf16* __restrict__ D = (mode == 1) ? D1 : (mode == 2) ? D2 : D0;

  const int tid  = threadIdx.x;
  const int lane = tid & 63;
  const int wave = tid >> 6;
  const int wm = wave >> 1, wn = wave & 1;
  const int quad = lane >> 4, l16 = lane & 15;
  const int m0 = blockIdx.x * 128;
  const int n0 = blockIdx.y * 128;

  // [0,16K): buf0 (As0 8K | Bs0 8K); [16K,32K): buf1; [16K,48K): Es (epilogue)
  __shared__ __align__(16) char gsm[49152];
  bf16* const smem = (bf16*)gsm;

  f32x4 acc[4][4] = {};

  const int ldrow = lane >> 2;
  const int ldcol = (lane & 3) * 8;

  auto stage = [&](int b, int k0) {
#pragma unroll
    for (int c = 0; c < 2; ++c) {
      const int chunk = wave * 2 + c;
      const int row = chunk * 16 + ldrow;
      async16(&A[(size_t)(m0 + row) * DMODEL + k0 + ldcol],
              &smem[b * 8192 + chunk * 512]);
      async16(&W[(size_t)(n0 + row) * DMODEL + k0 + ldcol],
              &smem[b * 8192 + 4096 + chunk * 512]);
    }
  };

  stage(0, 0);
  __syncthreads();

  for (int t = 0; t < 32; ++t) {
    const int cur = t & 1;
    if (t < 31) stage(cur ^ 1, (t + 1) * 32);  // prefetch flies over compute

    s16x8 af[4], bfr[4];
#pragma unroll
    for (int i = 0; i < 4; ++i)
      af[i] = *(const s16x8*)&smem[cur * 8192 + (wm * 64 + i * 16 + l16) * 32 + quad * 8];
#pragma unroll
    for (int j = 0; j < 4; ++j)
      bfr[j] = *(const s16x8*)&smem[cur * 8192 + 4096 + (wn * 64 + j * 16 + l16) * 32 + quad * 8];
#pragma unroll
    for (int i = 0; i < 4; ++i)
#pragma unroll
      for (int j = 0; j < 4; ++j)
        acc[i][j] = __builtin_amdgcn_mfma_f32_16x16x32_bf16(af[i], bfr[j],
                                                            acc[i][j], 0, 0, 0);
    // ONE barrier: drains this iter's prefetch (covered by the MFMA work)
    // and protects buf[cur] before iter t+1 restages into it.
    __syncthreads();
  }

  // ---- epilogue (Es aliased over buf1 + 16K more; K-loop is done) ----
  bf16* const Esw = (bf16*)(gsm + 16384) + wave * 4096;  // [64][64] per wave

  if (mode == 2) {  // transposed dump: Es[d_local][s_local]
#pragma unroll
    for (int i = 0; i < 4; ++i)
#pragma unroll
      for (int j = 0; j < 4; ++j)
#pragma unroll
        for (int r = 0; r < 4; ++r)
          Esw[(j * 16 + l16) * 64 + i * 16 + quad * 4 + r] =
              __float2bfloat16(acc[i][j][r]);
  } else {          // row-major dump: Es[s_local][d_local]
#pragma unroll
    for (int i = 0; i < 4; ++i)
#pragma unroll
      for (int j = 0; j < 4; ++j)
#pragma unroll
        for (int r = 0; r < 4; ++r)
          Esw[(i * 16 + quad * 4 + r) * 64 + j * 16 + l16] =
              __float2bfloat16(acc[i][j][r]);
  }
  __syncthreads();

  const int h = (n0 >> 6) + wn;         // wave's 64 cols = one head
  const int g  = lane >> 3;             // 0..7 row group
  const int c8 = (lane & 7) * 8;        // 0..56 col chunk (16B)

  if (mode == 2) {
#pragma unroll
    for (int t = 0; t < 8; ++t) {
      const int d = t * 8 + g;
      const s16x8 v = *(const s16x8*)&Esw[d * 64 + c8];
      *(s16x8*)&D[((size_t)h * DK + d) * SEQ + m0 + wm * 64 + c8] = v;
    }
  } else {
    // RoPE: pairs (c8+2k, c8+2k+1) in-lane; angle recurrence over t (rows +8).
    // mode 0 (Q): fold 0.125*log2e into cs/sn so attn can exp2 raw scores.
    const float qs = (mode == 0) ? SCALE_LOG2E : 1.0f;
    float sn[4], cs[4], s8[4], c8r[4], invf[4];
    const int srow0 = m0 + wm * 64 + g;
#pragma unroll
    for (int k = 0; k < 4; ++k) {
      const int p = (c8 >> 1) + k;
      invf[k] = __builtin_amdgcn_exp2f((float)p * (-2.0f / 64.0f) * LOG2_THETA);
      sincosf((float)srow0 * invf[k], &sn[k], &cs[k]);
      sincosf(8.0f * invf[k], &s8[k], &c8r[k]);
      sn[k] *= qs; cs[k] *= qs;
    }
#pragma unroll
    for (int t = 0; t < 8; ++t) {
      const int rl = t * 8 + g;
      union { bf16 h[8]; s16x8 v; } u, o;
      u.v = *(const s16x8*)&Esw[rl * 64 + c8];
#pragma unroll
      for (int k = 0; k < 4; ++k) {
        const float x0 = __bfloat162float(u.h[2 * k]);
        const float x1 = __bfloat162float(u.h[2 * k + 1]);
        o.h[2 * k]     = __float2bfloat16(x0 * cs[k] - x1 * sn[k]);
        o.h[2 * k + 1] = __float2bfloat16(x1 * cs[k] + x0 * sn[k]);
        const float ns_ = sn[k] * c8r[k] + cs[k] * s8[k];   // (scaled) recur
        cs[k] = cs[k] * c8r[k] - sn[k] * s8[k];
        sn[k] = ns_;
      }
      const int srow = m0 + wm * 64 + rl;
      *(s16x8*)&D[((size_t)h * SEQ + srow) * DK + c8] = o.v;
    }
  }
}

// Out-projection GEMM: Df[4096,1024] fp32 = A[4096,1024] @ W^T.
// 64x128 tiles -> 512 blocks (2/CU vs old 1/CU). 24KB LDS double-buffered,
// single-barrier K-loop. Wave (wm,wn) owns 32x64; acc[2][4].
__global__ __launch_bounds__(256)
void gemmo_kernel(const bf16* __restrict__ A, const bf16* __restrict__ W,
                  float* __restrict__ Df) {
  const int tid  = threadIdx.x;
  const int lane = tid & 63;
  const int wave = tid >> 6;
  const int wm = wave >> 1, wn = wave & 1;
  const int quad = lane >> 4, l16 = lane & 15;
  const int m0 = blockIdx.x * 64;
  const int n0 = blockIdx.y * 128;

  // per buf: As [64][32] @0 (2048 elems), Bs [128][32] @2048 (4096 elems)
  __shared__ __align__(16) bf16 sm[2][6144];

  f32x4 acc[2][4] = {};
  const int ldrow = lane >> 2;
  const int ldcol = (lane & 3) * 8;

  auto stage = [&](int b, int k0) {
    {  // A: 256 chunks, 1/thread
      const int row = wave * 16 + ldrow;
      async16(&A[(size_t)(m0 + row) * DMODEL + k0 + ldcol], &sm[b][wave * 512]);
    }
#pragma unroll
    for (int c = 0; c < 2; ++c) {  // B: 512 chunks, 2/thread
      const int row = (wave * 2 + c) * 16 + ldrow;
      async16(&W[(size_t)(n0 + row) * DMODEL + k0 + ldcol],
              &sm[b][2048 + (wave * 2 + c) * 512]);
    }
  };

  stage(0, 0);
  __syncthreads();

  for (int t = 0; t < 32; ++t) {
    const int cur = t & 1;
    if (t < 31) stage(cur ^ 1, (t + 1) * 32);

    s16x8 af[2], bfr[4];
#pragma unroll
    for (int i = 0; i < 2; ++i)
      af[i] = *(const s16x8*)&sm[cur][(wm * 32 + i * 16 + l16) * 32 + quad * 8];
#pragma unroll
    for (int j = 0; j < 4; ++j)
      bfr[j] = *(const s16x8*)&sm[cur][2048 + (wn * 64 + j * 16 + l16) * 32 + quad * 8];
#pragma unroll
    for (int i = 0; i < 2; ++i)
#pragma unroll
      for (int j = 0; j < 4; ++j)
        acc[i][j] = __builtin_amdgcn_mfma_f32_16x16x32_bf16(af[i], bfr[j],
                                                            acc[i][j], 0, 0, 0);
    __syncthreads();
  }

#pragma unroll
  for (int i = 0; i < 2; ++i)
#pragma unroll
    for (int j = 0; j < 4; ++j) {
      const int col = n0 + wn * 64 + j * 16 + l16;
#pragma unroll
      for (int r = 0; r < 4; ++r) {
        const int srow = m0 + wm * 32 + i * 16 + quad * 4 + r;
        Df[(size_t)srow * DMODEL + col] = acc[i][j][r];
      }
    }
}

// Flash attention. Block = one 64-q tile (1024 blocks, balanced decode).
// 2x2 wave split: wave (wq,wk) computes 32q x 32kv of each 64x64 tile.
// Swapped QK -> scores ARE the 16x16x16 A-fragment (no P LDS round-trip).
// R16: l via mfma16(P, ones) — lacc[gq][r] = l[q=quad*4+r], exactly oacc's
// row layout -> no shuffles, no per-iter VALU adds.
__global__ __launch_bounds__(256, 4)
void attn_kernel(const bf16* __restrict__ Q, const bf16* __restrict__ K,
                 const bf16* __restrict__ Vt, bf16* __restrict__ O) {
  const int tid  = threadIdx.x;
  const int lane = tid & 63;
  const int wave = tid >> 6;
  const int quad = lane >> 4, l16 = lane & 15;
  const int wq = wave & 1;               // q-half owner
  const int wk = wave >> 1;              // kv-half owner

  // balanced qb decode: blocks {i, i+256, i+512, i+768} co-reside on one CU
  // under round-robin; their lengths sum to 130 for every i.
  const int i  = (int)blockIdx.x;        // 0..1023
  const int j  = i & 255;
  const int vv = 3 - (i >> 8);           // 3,2,1,0 -> longest first
  const int h  = j & 15;
  const int a  = j >> 4;                 // 0..15
  const int qb = vv * 16 + ((vv & 1) ? (15 - a) : a);

  const bf16* __restrict__ Qh = Q + (size_t)h * SEQ * DK;
  const bf16* __restrict__ Kh = K + (size_t)h * SEQ * DK;
  const bf16* __restrict__ Vh = Vt + (size_t)h * DK * SEQ;

  // 32KB shared: loop phase = Ks[2][64*64] + Vs[2][64*64] (bf16, swizzled).
  // epilogue phase (after final barrier) re-uses it as:
  //   Ored f32[64][66] @0 (16896B) | lred f32[64] @16896 | Obuf bf16[64][72] @17408
  __shared__ __align__(16) char smemb[32768];
  bf16* __restrict__ smem = (bf16*)smemb;
  bf16* __restrict__ KsB = smem;          // [buf*4096]
  bf16* __restrict__ VsB = smem + 8192;   // [buf*4096]

  // staging lane geometry: 8 rows x 8 chunks per async16 set
  const int srow = lane >> 3;            // 0..7
  const int schk = (lane & 7) ^ srow;    // XOR-swizzled global chunk
  const int xsw  = l16 & 7;              // reader-side swizzle key

  const int q0 = qb * 64;
  const int qw = q0 + wq * 32;           // this wave's 32 Q rows
  const int nb = qb + 1;

  const short ONE = 0x3F80;
  const s16x4 ones4 = {ONE, ONE, ONE, ONE};

  // Q fragments (B-operand): aq[gq][half]
  s16x8 aq[2][2];
#pragma unroll
  for (int gq = 0; gq < 2; ++gq) {
    const size_t qr = (size_t)(qw + gq * 16 + l16) * DK;
    aq[gq][0] = *(const s16x8*)&Qh[qr + quad * 8];
    aq[gq][1] = *(const s16x8*)&Qh[qr + 32 + quad * 8];
  }

  f32x4 oacc[2][4] = {};   // [gq][d-block]: O[q=gq*16+quad*4+r][d=ns*16+l16]
  f32x4 lacc[2] = {};      // [gq]: l[q=gq*16+quad*4+r] (replicated over l16)

  // prologue: stage tile 0 into buffer 0
  {
#pragma unroll
    for (int c = 0; c < 2; ++c) {
      const int chunk = wave * 2 + c;
      async16(Kh + (size_t)(chunk * 8 + srow) * 64 + schk * 8,
              &KsB[chunk * 512]);
      async16(Vh + (size_t)(chunk * 8 + srow) * SEQ + schk * 8,
              &VsB[chunk * 512]);
    }
  }
  __syncthreads();

  for (int kb = 0; kb < nb; ++kb) {
    const int cur = kb & 1;
    // prefetch next tile into the other buffer (covered by this iter's work)
    if (kb + 1 < nb) {
      const int nxt = cur ^ 1;
      const int kv1 = (kb + 1) * 64;
      const bf16* kg = Kh + (size_t)kv1 * DK;
#pragma unroll
      for (int c = 0; c < 2; ++c) {
        const int chunk = wave * 2 + c;
        async16(kg + (size_t)(chunk * 8 + srow) * 64 + schk * 8,
                &KsB[nxt * 4096 + chunk * 512]);
        async16(Vh + (size_t)(chunk * 8 + srow) * SEQ + kv1 + schk * 8,
                &VsB[nxt * 4096 + chunk * 512]);
      }
    }

    const bf16* __restrict__ Ksc = &KsB[cur * 4096];
    const bf16* __restrict__ Vsc = &VsB[cur * 4096];

    // S^T = K*Q^T over this wave's 32-kv slice: per (gq,hh):
    // sc[gq][hh] D-layout: row quad*4+r = kv-local (within hh block), col l16 = q.
    f32x4 sc[2][2] = {};
    __builtin_amdgcn_s_setprio(1);
#pragma unroll
    for (int hh = 0; hh < 2; ++hh) {
      const bf16* kr = &Ksc[(wk * 32 + hh * 16 + l16) * 64];
      const s16x8 ak0 = *(const s16x8*)&kr[(quad ^ xsw) * 8];
      const s16x8 ak1 = *(const s16x8*)&kr[((quad + 4) ^ xsw) * 8];
#pragma unroll
      for (int gq = 0; gq < 2; ++gq) {
        sc[gq][hh] = __builtin_amdgcn_mfma_f32_16x16x32_bf16(ak0, aq[gq][0], sc[gq][hh], 0, 0, 0);
        sc[gq][hh] = __builtin_amdgcn_mfma_f32_16x16x32_bf16(ak1, aq[gq][1], sc[gq][hh], 0, 0, 0);
      }
    }
    __builtin_amdgcn_s_setprio(0);

    // causal mask on diagonal tile: kv > q
    if (kb == nb - 1) {
#pragma unroll
      for (int gq = 0; gq < 2; ++gq) {
        const int lim = wq * 32 + gq * 16 + l16 - wk * 32 - quad * 4;
#pragma unroll
        for (int hh = 0; hh < 2; ++hh)
#pragma unroll
          for (int r = 0; r < 4; ++r)
            if (hh * 16 + r > lim) sc[gq][hh][r] = -1e30f;
      }
    }

    // p = exp2(score) (Q pre-scaled, raw v_exp_f32). Packed s16x4 per (gq,hh)
    // IS the 16x16x16 A-fragment (A[row=l16][k=quad*4+i]) — no LDS, no shuffle.
    s16x4 ap[2][2];
#pragma unroll
    for (int gq = 0; gq < 2; ++gq)
#pragma unroll
      for (int hh = 0; hh < 2; ++hh) {
        union { bf16 b[4]; s16x4 v; } pk;
#pragma unroll
        for (int r = 0; r < 4; ++r)
          pk.b[r] = __float2bfloat16(__builtin_amdgcn_exp2f(sc[gq][hh][r]));
        ap[gq][hh] = pk.v;
      }

    // PV via 16x16x16: B[k=kv=quad*4+i][col=d=l16] from Vt[d][kv] slice.
    __builtin_amdgcn_s_setprio(1);
#pragma unroll
    for (int hh = 0; hh < 2; ++hh) {
      const int cg = wk * 4 + hh * 2 + (quad >> 1);      // global 16B chunk
      const int eo = ((cg ^ xsw) << 3) + (quad & 1) * 4; // elem offset in row
#pragma unroll
      for (int ns = 0; ns < 4; ++ns) {
        const s16x4 bv = *(const s16x4*)&Vsc[(ns * 16 + l16) * 64 + eo];
#pragma unroll
        for (int gq = 0; gq < 2; ++gq)
          oacc[gq][ns] = mfma16(ap[gq][hh], bv, oacc[gq][ns]);
      }
    }
    // l row-sums on the MFMA pipe (replaces 16 VALU adds)
#pragma unroll
    for (int gq = 0; gq < 2; ++gq)
#pragma unroll
      for (int hh = 0; hh < 2; ++hh)
        lacc[gq] = mfma16(ap[gq][hh], ones4, lacc[gq]);
    __builtin_amdgcn_s_setprio(0);

    // ONE barrier: drains the prefetch (covered by compute above) and
    // protects buf[cur] from restaging next iteration.
    __syncthreads();
  }

  // ---- cross-wave (wk) reduction + store ----
  float* __restrict__ Ored = (float*)smemb;            // [64][66]
  float* __restrict__ lred = (float*)(smemb + 16896);  // [64]
  bf16*  __restrict__ Obuf = (bf16*)(smemb + 17408);   // [64][72]

  if (wk == 0) {
    if (l16 == 0)
#pragma unroll
      for (int gq = 0; gq < 2; ++gq)
#pragma unroll
        for (int r = 0; r < 4; ++r)
          lred[wq * 32 + gq * 16 + quad * 4 + r] = lacc[gq][r];
  } else {
#pragma unroll
    for (int gq = 0; gq < 2; ++gq)
#pragma unroll
      for (int ns = 0; ns < 4; ++ns)
#pragma unroll
        for (int r = 0; r < 4; ++r)
          Ored[(wq * 32 + gq * 16 + quad * 4 + r) * 66 + ns * 16 + l16] =
              oacc[gq][ns][r];
  }
  __syncthreads();
  if (wk == 1 && l16 == 0) {
#pragma unroll
    for (int gq = 0; gq < 2; ++gq)
#pragma unroll
      for (int r = 0; r < 4; ++r)
        lred[wq * 32 + gq * 16 + quad * 4 + r] += lacc[gq][r];
  }
  __syncthreads();
  if (wk == 0) {
#pragma unroll
    for (int gq = 0; gq < 2; ++gq) {
      float rl[4];
#pragma unroll
      for (int r = 0; r < 4; ++r)
        rl[r] = __builtin_amdgcn_rcpf(lred[wq * 32 + gq * 16 + quad * 4 + r]);
#pragma unroll
      for (int ns = 0; ns < 4; ++ns)
#pragma unroll
        for (int r = 0; r < 4; ++r) {
          const int row = wq * 32 + gq * 16 + quad * 4 + r;
          const float v = oacc[gq][ns][r] + Ored[row * 66 + ns * 16 + l16];
          Obuf[row * 72 + ns * 16 + l16] = __float2bfloat16(v * rl[r]);
        }
    }
  }
  __syncthreads();
  // cooperative coalesced store: 64 rows x 128B, 2 passes of 256x16B
#pragma unroll
  for (int p = 0; p < 2; ++p) {
    const int row = p * 32 + (tid >> 3);
    const int c8 = (tid & 7) * 8;
    const s16x8 v = *(const s16x8*)&Obuf[row * 72 + c8];
    *(s16x8*)&O[(size_t)(q0 + row) * DMODEL + h * DK + c8] = v;
  }
}

extern "C" void kernel_launch(void* const* d_in, const int* in_sizes, int n_in,
                              void* d_out, int out_size, void* d_ws, size_t ws_size,
                              hipStream_t stream) {
  const float* x  = (const float*)d_in[0];
  const float* Wq = (const float*)d_in[1];
  const float* Wk = (const float*)d_in[2];
  const float* Wv = (const float*)d_in[3];
  const float* Wo = (const float*)d_in[4];
  float* out = (float*)d_out;

  bf16* ws = (bf16*)d_ws;
  bf16* xb   = ws;
  bf16* Wqb  = xb  + (size_t)SEQ * DMODEL;
  bf16* Wkb  = Wqb + (size_t)DMODEL * DMODEL;
  bf16* Wvb  = Wkb + (size_t)DMODEL * DMODEL;
  bf16* Wob  = Wvb + (size_t)DMODEL * DMODEL;
  bf16* Qb   = Wob + (size_t)DMODEL * DMODEL;
  bf16* Kb   = Qb  + (size_t)SEQ * DMODEL;
  bf16* Vtb  = Kb  + (size_t)SEQ * DMODEL;
  bf16* Attn = Vtb + (size_t)SEQ * DMODEL;

  conv_kernel<<<dim3(512, 1, 5), 256, 0, stream>>>(
      x, Wq, Wk, Wv, Wo, xb, Wqb, Wkb, Wvb, Wob);
  gemm_kernel<<<dim3(SEQ / 128, DMODEL / 128, 3), 256, 0, stream>>>(
      xb, Wqb, Wkb, Wvb, Qb, Kb, Vtb);
  attn_kernel<<<dim3(64 * NHEADS), 256, 0, stream>>>(Qb, Kb, Vtb, Attn);
  gemmo_kernel<<<dim3(SEQ / 64, DMODEL / 128), 256, 0, stream>>>(
      Attn, Wob, out);
}